// Round 14
// baseline (276.363 us; speedup 1.0000x reference)
//
#include <hip/hip_runtime.h>

// GMSA r14: conv_in -> 128-thread blocks (64 px, grid 8192): same 3-phase
// ping-pong as r13 but 4 independent barrier domains/CU instead of 2 ->
// better load/compute overlap across blocks. attn/conv_out r13 verbatim.

typedef _Float16 f16x8 __attribute__((ext_vector_type(8)));
typedef _Float16 f16x4 __attribute__((ext_vector_type(4)));
typedef float    f32x4 __attribute__((ext_vector_type(4)));

__device__ inline float exp2_fast(float x) {
    float r; asm("v_exp_f32 %0, %1" : "=v"(r) : "v"(x)); return r;
}
__device__ inline unsigned pkrtz(float a, float b) {
    return __builtin_bit_cast(unsigned, __builtin_amdgcn_cvt_pkrtz(a, b));
}

// ---- one-shot weight prep -------------------------------------------------
__global__ __launch_bounds__(256) void k_prep(
    const float* __restrict__ w_in, const float* __restrict__ b_in,
    const float* __restrict__ gma, const float* __restrict__ bta,
    const float* __restrict__ mu,  const float* __restrict__ var,
    const float* __restrict__ w_out,
    _Float16* __restrict__ wf, float* __restrict__ bs, _Float16* __restrict__ wo)
{
    const int t = threadIdx.x;
    if (t < 192) {
        const float qs = ((t & 63) < 32) ? 1.2011224087864498f : 1.0f; // sqrt(log2e)
        float iv = gma[t] * rsqrtf(var[t] + 1e-5f);
        float s  = iv * qs;
        bs[t] = (b_in[t]*iv + bta[t] - mu[t]*iv) * qs;
        #pragma unroll
        for (int c4 = 0; c4 < 96; c4 += 4) {
            float4 w = *reinterpret_cast<const float4*>(w_in + t*96 + c4);
            f16x4 h;
            h[0]=(_Float16)(w.x*s); h[1]=(_Float16)(w.y*s);
            h[2]=(_Float16)(w.z*s); h[3]=(_Float16)(w.w*s);
            *reinterpret_cast<f16x4*>(wf + t*96 + c4) = h;
        }
    }
    if (t < 96) {
        #pragma unroll
        for (int c4 = 0; c4 < 96; c4 += 4) {
            float4 w = *reinterpret_cast<const float4*>(w_out + t*96 + c4);
            f16x4 h;
            h[0]=(_Float16)w.x; h[1]=(_Float16)w.y;
            h[2]=(_Float16)w.z; h[3]=(_Float16)w.w;
            *reinterpret_cast<f16x4*>(wo + t*96 + c4) = h;
        }
    }
}

// ---- conv_in: 128 threads, 64 px/block, D[192 o][64 px] -------------------
__global__ __launch_bounds__(128) void k_conv_in(
    const float* __restrict__ x, const _Float16* __restrict__ wf,
    const float* __restrict__ bs,
    _Float16* __restrict__ q0, _Float16* __restrict__ v0,
    _Float16* __restrict__ q1, _Float16* __restrict__ v1,
    _Float16* __restrict__ q2, _Float16* __restrict__ v2)
{
    __shared__ unsigned xs2[2][16*68];    // dword = f16 pair (2c2,2c2+1), 64px+pad
    const int t  = threadIdx.x;
    const int oh = t >> 6, ln = t & 63;   // wave = o-half; both waves: all 64 px
    const int lo = ln & 15, hi = ln >> 4;

    const int pixbase = blockIdx.x * 64;
    const int b   = pixbase >> 16;
    const int rem = pixbase & 65535;
    const int hh  = rem >> 8;
    const int ww0 = rem & 255;

    const int r0 = t >> 4;                // pair-row 0..7 (and +8)
    const int q4 = (t & 15) << 2;
    const float* xb = x + (size_t)b*96*65536 + rem + q4;

    float4 L0, L1, L2, L3;

#define CLOAD(c0) { \
    L0 = *reinterpret_cast<const float4*>(xb + (size_t)(c0 + 2*r0     )*65536); \
    L1 = *reinterpret_cast<const float4*>(xb + (size_t)(c0 + 2*r0 +  1)*65536); \
    L2 = *reinterpret_cast<const float4*>(xb + (size_t)(c0 + 2*r0 + 16)*65536); \
    L3 = *reinterpret_cast<const float4*>(xb + (size_t)(c0 + 2*r0 + 17)*65536); }
#define CWRITE(bf) { \
    uint4 u0, u1; \
    u0.x = pkrtz(L0.x, L1.x); u0.y = pkrtz(L0.y, L1.y); \
    u0.z = pkrtz(L0.z, L1.z); u0.w = pkrtz(L0.w, L1.w); \
    u1.x = pkrtz(L2.x, L3.x); u1.y = pkrtz(L2.y, L3.y); \
    u1.z = pkrtz(L2.z, L3.z); u1.w = pkrtz(L2.w, L3.w); \
    *reinterpret_cast<uint4*>(&xs2[bf][ r0     *68 + q4]) = u0; \
    *reinterpret_cast<uint4*>(&xs2[bf][(r0 + 8)*68 + q4]) = u1; }
#define CCOMP(bf, ks) { \
    _Pragma("unroll") for (int cf = 0; cf < 4; ++cf) { \
        const unsigned* bp = &xs2[bf][hi*4*68 + cf*16 + lo]; \
        uint4 u; u.x = bp[0]; u.y = bp[68]; u.z = bp[136]; u.w = bp[204]; \
        f16x8 bfv = __builtin_bit_cast(f16x8, u); \
        _Pragma("unroll") for (int rf = 0; rf < 6; ++rf) \
            acc[rf][cf] = __builtin_amdgcn_mfma_f32_16x16x32_f16( \
                              af[rf][ks], bfv, acc[rf][cf], 0,0,0); } }

    CLOAD(0);

    f16x8 af[6][3];
    const _Float16* wrow0 = wf + (size_t)(oh*96 + lo)*96 + hi*8;
    #pragma unroll
    for (int rf = 0; rf < 6; ++rf)
        #pragma unroll
        for (int ks = 0; ks < 3; ++ks)
            af[rf][ks] = *reinterpret_cast<const f16x8*>(wrow0 + rf*16*96 + ks*32);

    f32x4 acc[6][4];
    #pragma unroll
    for (int rf = 0; rf < 6; ++rf)
        #pragma unroll
        for (int cf = 0; cf < 4; ++cf) acc[rf][cf] = f32x4{0.f,0.f,0.f,0.f};

    CWRITE(0);
    __syncthreads();
    CLOAD(32);                 // chunk1 in flight under COMPUTE(0)
    CCOMP(0, 0);
    CWRITE(1);
    __syncthreads();
    CLOAD(64);                 // chunk2 in flight under COMPUTE(1)
    CCOMP(1, 1);
    CWRITE(0);                 // safe: all waves left chunk0 at last barrier
    __syncthreads();
    CCOMP(0, 2);

    int ro[3][4];
    #pragma unroll
    for (int i = 0; i < 3; ++i) {
        const int lg = 2 + i;
        const int ws = 1 << lg;
        const int sft = ws >> 1;
        const int nblk = 256 >> lg;
        int h  = (hh - sft) & 255;
        int nbrow = (b*nblk + (h >> lg))*nblk;
        int hr = h & (ws-1);
        #pragma unroll
        for (int cf = 0; cf < 4; ++cf) {
            int w = (ww0 + cf*16 + lo - sft) & 255;
            ro[i][cf] = (nbrow + (w >> lg))*(ws*ws) + hr*ws + (w & (ws-1));
        }
    }
    #pragma unroll
    for (int rf = 0; rf < 6; ++rf) {
        const int base = oh*96 + rf*16;
        const int o0i  = base + hi*4;
        const int sc   = base >> 6;
        const bool isv = (base & 32) != 0;
        const int c32  = o0i & 31;
        float4 bi = *reinterpret_cast<const float4*>(bs + o0i);
        _Float16* tb = (sc == 0) ? (isv ? v0 : q0)
                     : (sc == 1) ? (isv ? v1 : q1)
                                 : (isv ? v2 : q2);
        #pragma unroll
        for (int cf = 0; cf < 4; ++cf) {
            f16x4 hv;
            hv[0] = (_Float16)(acc[rf][cf][0] + bi.x);
            hv[1] = (_Float16)(acc[rf][cf][1] + bi.y);
            hv[2] = (_Float16)(acc[rf][cf][2] + bi.z);
            hv[3] = (_Float16)(acc[rf][cf][3] + bi.w);
            *reinterpret_cast<f16x4*>(tb + (size_t)ro[sc][cf]*32 + c32) = hv;
        }
    }
#undef CLOAD
#undef CWRITE
#undef CCOMP
}

// ---- Flash attention body (r13 verbatim: per-rb fused P+PV) ---------------
template<int GROUP>
__device__ __forceinline__ void attn_body(
    int bid, uint4* Kl, _Float16* Vt, _Float16* Pl,
    const _Float16* __restrict__ Q, const _Float16* __restrict__ Ks,
    const _Float16* Vs, _Float16* O)
{
    constexpr int S   = (GROUP==0) ? 16 : (GROUP==1) ? 64 : 256;
    constexpr int GB  = 256 / S;
    constexpr int KT  = (S < 32) ? 16 : 32;
    constexpr int NT  = S / KT;
    constexpr int CBS = KT / 16;

    const int t = threadIdx.x;
    {
        const int g = t / S, j = t % S;
        const int bq = bid * GB + g;
        int krow, vrow;
        if constexpr (GROUP == 0) {
            krow = (bq >> 2)*64  + (j << 2) + (bq & 3);
            vrow = (bq >> 4)*256 + (j << 4) + (bq & 15);
        } else if constexpr (GROUP == 1) {
            krow = (bq >> 2)*256 + (j << 2) + (bq & 3);
            vrow = ((bq << 2) + (j & 3))*16 + (j >> 2);
        } else {
            krow = ((bq << 4) + (j & 15))*16 + (j >> 4);
            vrow = ((bq << 2) + (j & 3))*64 + (j >> 2);
        }
        const uint4* ks = reinterpret_cast<const uint4*>(Ks + (size_t)krow*32);
        uint4 ka = ks[0], kb = ks[1], kc = ks[2], kd = ks[3];
        Kl[0*256 + t] = ka; Kl[1*256 + t] = kb;
        Kl[2*256 + t] = kc; Kl[3*256 + t] = kd;
        union { uint4 u4[4]; _Float16 h[32]; } vb;
        const uint4* vs = reinterpret_cast<const uint4*>(Vs + (size_t)vrow*32);
        vb.u4[0] = vs[0]; vb.u4[1] = vs[1]; vb.u4[2] = vs[2]; vb.u4[3] = vs[3];
        #pragma unroll
        for (int d = 0; d < 32; ++d) Vt[d*264 + t] = vb.h[d];
        Vt[(t >> 3)*264 + 256 + (t & 7)] = (_Float16)0.f;
        if (t < 8) Vt[32*264 + t] = (_Float16)0.f;
    }
    const int wv = t >> 6, ln = t & 63;
    const int lo = ln & 15, hi = ln >> 4;
    _Float16* Pw = Pl + wv*(16*40);
    if constexpr (S == 16) {
        uint* pw32 = reinterpret_cast<uint*>(Pw);
        pw32[(ln >> 2)*20 +  8 + (ln & 3)] = 0u;
        pw32[(ln >> 2)*20 + 12 + (ln & 3)] = 0u;
    }
    __syncthreads();

    const int rowbase = bid*256 + wv*64;
    f16x8 qf[4];
    #pragma unroll
    for (int rb = 0; rb < 4; ++rb) {
        uint4 qv = *reinterpret_cast<const uint4*>(
            Q + ((size_t)(rowbase + rb*16 + lo))*32 + hi*8);
        qf[rb] = __builtin_bit_cast(f16x8, qv);
    }

    f32x4 ofr[4][2];
    float m[4], ls[4];
    #pragma unroll
    for (int rb = 0; rb < 4; ++rb) {
        m[rb] = -1e30f; ls[rb] = 0.f;
        ofr[rb][0] = f32x4{0.f,0.f,0.f,0.f};
        ofr[rb][1] = f32x4{0.f,0.f,0.f,0.f};
    }
    const f32x4 zf = f32x4{0.f,0.f,0.f,0.f};

    for (int tt = 0; tt < NT; ++tt) {
        f16x8 bk[CBS];
        if constexpr (S != 16) {
            const int wb = (S == 64) ? wv*64 : 0;
            #pragma unroll
            for (int cb = 0; cb < CBS; ++cb) {
                int key = wb + tt*KT + cb*16 + lo;
                bk[cb] = __builtin_bit_cast(f16x8, Kl[hi*256 + key]);
            }
        }

        #pragma unroll
        for (int rb = 0; rb < 4; ++rb) {
            f32x4 sf[CBS];
            if constexpr (S == 16) {
                int key = wv*64 + rb*16 + lo;
                f16x8 bk0 = __builtin_bit_cast(f16x8, Kl[hi*256 + key]);
                sf[0] = __builtin_amdgcn_mfma_f32_16x16x32_f16(bk0, qf[rb], zf, 0,0,0);
            } else {
                #pragma unroll
                for (int cb = 0; cb < CBS; ++cb)
                    sf[cb] = __builtin_amdgcn_mfma_f32_16x16x32_f16(bk[cb], qf[rb], zf, 0,0,0);
            }

            float tm = sf[0][0];
            #pragma unroll
            for (int cb = 0; cb < CBS; ++cb)
                #pragma unroll
                for (int r = 0; r < 4; ++r)
                    if (cb | r) tm = fmaxf(tm, sf[cb][r]);
            tm = fmaxf(tm, __shfl_xor(tm, 16));
            tm = fmaxf(tm, __shfl_xor(tm, 32));
            float mn = fmaxf(m[rb], tm);
            float sc = exp2_fast(m[rb] - mn);
            m[rb] = mn;
            float ps = 0.f;
            #pragma unroll
            for (int cb = 0; cb < CBS; ++cb) {
                float p0 = exp2_fast(sf[cb][0] - mn);
                float p1 = exp2_fast(sf[cb][1] - mn);
                float p2 = exp2_fast(sf[cb][2] - mn);
                float p3 = exp2_fast(sf[cb][3] - mn);
                ps += (p0+p1)+(p2+p3);
                unsigned w01 = pkrtz(p0, p1);
                unsigned w23 = pkrtz(p2, p3);
                _Float16* pp = Pw + lo*40 + cb*16 + hi*4;
                *reinterpret_cast<unsigned*>(pp)     = w01;
                *reinterpret_cast<unsigned*>(pp + 2) = w23;
            }
            ls[rb] = ls[rb]*sc + ps;
            float s0 = __shfl(sc, hi*4 + 0);
            float s1 = __shfl(sc, hi*4 + 1);
            float s2 = __shfl(sc, hi*4 + 2);
            float s3 = __shfl(sc, hi*4 + 3);
            ofr[rb][0][0]*=s0; ofr[rb][0][1]*=s1; ofr[rb][0][2]*=s2; ofr[rb][0][3]*=s3;
            ofr[rb][1][0]*=s0; ofr[rb][1][1]*=s1; ofr[rb][1][2]*=s2; ofr[rb][1][3]*=s3;

            f16x8 pa = *reinterpret_cast<const f16x8*>(Pw + lo*40 + hi*8);
            const int wb2 = (S == 16) ? wv*64 + rb*16 : (S == 64) ? wv*64 : 0;
            const int key0 = wb2 + tt*KT + hi*8;
            #pragma unroll
            for (int dcb = 0; dcb < 2; ++dcb) {
                f16x8 bv = *reinterpret_cast<const f16x8*>(Vt + (dcb*16 + lo)*264 + key0);
                ofr[rb][dcb] = __builtin_amdgcn_mfma_f32_16x16x32_f16(pa, bv, ofr[rb][dcb], 0,0,0);
            }
        }
    }

    #pragma unroll
    for (int rb = 0; rb < 4; ++rb) {
        float v = ls[rb];
        v += __shfl_xor(v, 16);
        v += __shfl_xor(v, 32);
        float linv = 1.f / v;
        float l0 = __shfl(linv, hi*4 + 0);
        float l1 = __shfl(linv, hi*4 + 1);
        float l2 = __shfl(linv, hi*4 + 2);
        float l3 = __shfl(linv, hi*4 + 3);
        #pragma unroll
        for (int dcb = 0; dcb < 2; ++dcb) {
            float lr[4] = {l0, l1, l2, l3};
            #pragma unroll
            for (int r = 0; r < 4; ++r) {
                float ov = ofr[rb][dcb][r] * lr[r];
                int row = rowbase + rb*16 + hi*4 + r;
                O[(size_t)row*32 + dcb*16 + lo] = (_Float16)ov;
            }
        }
    }
}

__global__ __launch_bounds__(256) void k_attn_all(
    const _Float16* __restrict__ q0, const _Float16* __restrict__ v0,
    const _Float16* __restrict__ q1, const _Float16* __restrict__ v1,
    const _Float16* __restrict__ q2, const _Float16* __restrict__ v2)
{
    __shared__ __align__(16) char smem[16384 + 16912 + 5120];
    uint4*    Kl = reinterpret_cast<uint4*>(smem);
    _Float16* Vt = reinterpret_cast<_Float16*>(smem + 16384);
    _Float16* Pl = reinterpret_cast<_Float16*>(smem + 16384 + 16912);
    const int bid = (int)blockIdx.x;
    if (bid < 2048)
        attn_body<0>(bid, Kl, Vt, Pl, q0, q1, v2, const_cast<_Float16*>(v2));
    else if (bid < 4096)
        attn_body<1>(bid - 2048, Kl, Vt, Pl, q1, q2, v0, const_cast<_Float16*>(v0));
    else
        attn_body<2>(bid - 4096, Kl, Vt, Pl, q2, q0, v1, const_cast<_Float16*>(v1));
}

// ---- conv_out (r13 verbatim) ----------------------------------------------
__global__ __launch_bounds__(256) void k_conv_out(
    const _Float16* __restrict__ o0, const _Float16* __restrict__ o1,
    const _Float16* __restrict__ o2, const _Float16* __restrict__ wo,
    const float* __restrict__ b_out, float* __restrict__ out)
{
    constexpr int YS = 104;
    __shared__ _Float16 yt[256*YS];
    const int t  = threadIdx.x;
    const int wv = t >> 6, ln = t & 63;
    const int lo = ln & 15, hi = ln >> 4;
    const int bid = (int)blockIdx.x;
    const int swz = (bid & 7)*256 + (bid >> 3);
    const int b = swz >> 8;
    const int h = swz & 255;

    #pragma unroll
    for (int i = 0; i < 3; ++i) {
        const int lg = 2 + i;
        const int ws = 1 << lg;
        const int sft = ws >> 1;
        const int nblk = 256 >> lg;
        int hh = (h - sft) & 255;
        int w  = (t - sft) & 255;
        int nb = (b*nblk + (hh >> lg))*nblk + (w >> lg);
        int roff = nb*(ws*ws) + (hh & (ws-1))*ws + (w & (ws-1));
        const uint4* src = reinterpret_cast<const uint4*>(
            (i==0 ? o0 : i==1 ? o1 : o2) + (size_t)roff*32);
        uint4 r0 = src[0], r1 = src[1], r2 = src[2], r3 = src[3];
        uint4* dst = reinterpret_cast<uint4*>(&yt[t*YS + i*32]);
        dst[0] = r0; dst[1] = r1; dst[2] = r2; dst[3] = r3;
    }

    f16x8 af[6][3];
    #pragma unroll
    for (int rf = 0; rf < 6; ++rf)
        #pragma unroll
        for (int ks = 0; ks < 3; ++ks)
            af[rf][ks] = *reinterpret_cast<const f16x8*>(
                wo + (rf*16 + lo)*96 + ks*32 + hi*8);
    __syncthreads();

    f32x4 acc[6][4];
    #pragma unroll
    for (int rf = 0; rf < 6; ++rf)
        #pragma unroll
        for (int cf = 0; cf < 4; ++cf) acc[rf][cf] = f32x4{0.f,0.f,0.f,0.f};

    #pragma unroll
    for (int cf = 0; cf < 4; ++cf) {
        const int px = wv*64 + cf*16 + lo;
        #pragma unroll
        for (int ks = 0; ks < 3; ++ks) {
            f16x8 bfv = *reinterpret_cast<const f16x8*>(&yt[px*YS + ks*32 + hi*8]);
            #pragma unroll
            for (int rf = 0; rf < 6; ++rf)
                acc[rf][cf] = __builtin_amdgcn_mfma_f32_16x16x32_f16(
                                  af[rf][ks], bfv, acc[rf][cf], 0,0,0);
        }
    }

    const size_t obase = (size_t)b*96*65536 + (size_t)h*256;
    #pragma unroll
    for (int rf = 0; rf < 6; ++rf) {
        const int oo = rf*16 + hi*4;
        float4 bi = *reinterpret_cast<const float4*>(b_out + oo);
        #pragma unroll
        for (int cf = 0; cf < 4; ++cf) {
            const int px = wv*64 + cf*16 + lo;
            out[obase + (size_t)(oo+0)*65536 + px] = acc[rf][cf][0] + bi.x;
            out[obase + (size_t)(oo+1)*65536 + px] = acc[rf][cf][1] + bi.y;
            out[obase + (size_t)(oo+2)*65536 + px] = acc[rf][cf][2] + bi.z;
            out[obase + (size_t)(oo+3)*65536 + px] = acc[rf][cf][3] + bi.w;
        }
    }
}

extern "C" void kernel_launch(void* const* d_in, const int* in_sizes, int n_in,
                              void* d_out, int out_size, void* d_ws, size_t ws_size,
                              hipStream_t stream)
{
    const float* x     = (const float*)d_in[0];
    const float* w_in  = (const float*)d_in[1];
    const float* b_in  = (const float*)d_in[2];
    const float* gma   = (const float*)d_in[3];
    const float* bta   = (const float*)d_in[4];
    const float* mu    = (const float*)d_in[5];
    const float* var   = (const float*)d_in[6];
    const float* w_out = (const float*)d_in[7];
    const float* b_out = (const float*)d_in[8];
    float* out = (float*)d_out;

    _Float16* W = (_Float16*)d_ws;
    const size_t M = 16777216;
    _Float16 *q0 = W,       *v0 = W +   M, *q1 = W + 2*M,
             *v1 = W + 3*M, *q2 = W + 4*M, *v2 = W + 5*M;
    _Float16* wf = W + 6*M;
    float*    bs = (float*)(W + 6*M + 18432);
    _Float16* wo = W + 6*M + 18432 + 384;

    k_prep<<<1, 256, 0, stream>>>(w_in, b_in, gma, bta, mu, var, w_out, wf, bs, wo);
    k_conv_in<<<8192, 128, 0, stream>>>(x, wf, bs, q0, v0, q1, v1, q2, v2);
    k_attn_all<<<6144, 256, 0, stream>>>(q0, v0, q1, v1, q2, v2);
    k_conv_out<<<2048, 256, 0, stream>>>(v2, v0, v1, wo, b_out, out);
}

// Round 15
// 273.415 us; speedup vs baseline: 1.0108x; 1.0108x over previous
//
#include <hip/hip_runtime.h>

// GMSA r15: conv_in re-tiled for occupancy: 4 waves x (48 o x 64 px), acc 48
// + af 36 -> ~125 regs/wave -> 4 waves/SIMD (was 2: 216 regs incl. unified
// AGPR). XCD-contiguous tile swizzle. attn/conv_out r13 verbatim.

typedef _Float16 f16x8 __attribute__((ext_vector_type(8)));
typedef _Float16 f16x4 __attribute__((ext_vector_type(4)));
typedef float    f32x4 __attribute__((ext_vector_type(4)));

__device__ inline float exp2_fast(float x) {
    float r; asm("v_exp_f32 %0, %1" : "=v"(r) : "v"(x)); return r;
}
__device__ inline unsigned pkrtz(float a, float b) {
    return __builtin_bit_cast(unsigned, __builtin_amdgcn_cvt_pkrtz(a, b));
}

// ---- one-shot weight prep -------------------------------------------------
__global__ __launch_bounds__(256) void k_prep(
    const float* __restrict__ w_in, const float* __restrict__ b_in,
    const float* __restrict__ gma, const float* __restrict__ bta,
    const float* __restrict__ mu,  const float* __restrict__ var,
    const float* __restrict__ w_out,
    _Float16* __restrict__ wf, float* __restrict__ bs, _Float16* __restrict__ wo)
{
    const int t = threadIdx.x;
    if (t < 192) {
        const float qs = ((t & 63) < 32) ? 1.2011224087864498f : 1.0f; // sqrt(log2e)
        float iv = gma[t] * rsqrtf(var[t] + 1e-5f);
        float s  = iv * qs;
        bs[t] = (b_in[t]*iv + bta[t] - mu[t]*iv) * qs;
        #pragma unroll
        for (int c4 = 0; c4 < 96; c4 += 4) {
            float4 w = *reinterpret_cast<const float4*>(w_in + t*96 + c4);
            f16x4 h;
            h[0]=(_Float16)(w.x*s); h[1]=(_Float16)(w.y*s);
            h[2]=(_Float16)(w.z*s); h[3]=(_Float16)(w.w*s);
            *reinterpret_cast<f16x4*>(wf + t*96 + c4) = h;
        }
    }
    if (t < 96) {
        #pragma unroll
        for (int c4 = 0; c4 < 96; c4 += 4) {
            float4 w = *reinterpret_cast<const float4*>(w_out + t*96 + c4);
            f16x4 h;
            h[0]=(_Float16)w.x; h[1]=(_Float16)w.y;
            h[2]=(_Float16)w.z; h[3]=(_Float16)w.w;
            *reinterpret_cast<f16x4*>(wo + t*96 + c4) = h;
        }
    }
}

// ---- conv_in: 64-px tile, 4 waves x (48 o x 64 px), low-reg ---------------
__global__ __launch_bounds__(256) void k_conv_in(
    const float* __restrict__ x, const _Float16* __restrict__ wf,
    const float* __restrict__ bs,
    _Float16* __restrict__ q0, _Float16* __restrict__ v0,
    _Float16* __restrict__ q1, _Float16* __restrict__ v1,
    _Float16* __restrict__ q2, _Float16* __restrict__ v2)
{
    __shared__ unsigned xs2[2][16*68];    // dword = f16 pair (2c2,2c2+1) per px
    const int t  = threadIdx.x;
    const int wv = t >> 6, ln = t & 63;
    const int lo = ln & 15, hi = ln >> 4;

    const int bid  = (int)blockIdx.x;
    const int tile = (bid & 7)*1024 + (bid >> 3);   // XCD-contiguous px ranges
    const int pixbase = tile * 64;
    const int b   = pixbase >> 16;
    const int rem = pixbase & 65535;
    const int hh  = rem >> 8;
    const int ww0 = rem & 255;

    const int r0 = t >> 4;                // pair-row 0..15
    const int q4 = (t & 15) << 2;
    const float* xb = x + (size_t)b*96*65536 + rem + q4;

    float4 L0, L1;

#define CLOAD(c0) { \
    L0 = *reinterpret_cast<const float4*>(xb + (size_t)(c0 + 2*r0    )*65536); \
    L1 = *reinterpret_cast<const float4*>(xb + (size_t)(c0 + 2*r0 + 1)*65536); }
#define CWRITE(bf) { \
    uint4 u0; \
    u0.x = pkrtz(L0.x, L1.x); u0.y = pkrtz(L0.y, L1.y); \
    u0.z = pkrtz(L0.z, L1.z); u0.w = pkrtz(L0.w, L1.w); \
    *reinterpret_cast<uint4*>(&xs2[bf][r0*68 + q4]) = u0; }
#define CCOMP(bf, ks) { \
    _Pragma("unroll") for (int cf = 0; cf < 4; ++cf) { \
        const unsigned* bp = &xs2[bf][hi*4*68 + cf*16 + lo]; \
        uint4 u; u.x = bp[0]; u.y = bp[68]; u.z = bp[136]; u.w = bp[204]; \
        f16x8 bfv = __builtin_bit_cast(f16x8, u); \
        _Pragma("unroll") for (int rf = 0; rf < 3; ++rf) \
            acc[rf][cf] = __builtin_amdgcn_mfma_f32_16x16x32_f16( \
                              af[rf][ks], bfv, acc[rf][cf], 0,0,0); } }

    CLOAD(0);

    f16x8 af[3][3];
    const _Float16* wrow0 = wf + (size_t)(wv*48 + lo)*96 + hi*8;
    #pragma unroll
    for (int rf = 0; rf < 3; ++rf)
        #pragma unroll
        for (int ks = 0; ks < 3; ++ks)
            af[rf][ks] = *reinterpret_cast<const f16x8*>(wrow0 + rf*16*96 + ks*32);

    f32x4 acc[3][4];
    #pragma unroll
    for (int rf = 0; rf < 3; ++rf)
        #pragma unroll
        for (int cf = 0; cf < 4; ++cf) acc[rf][cf] = f32x4{0.f,0.f,0.f,0.f};

    CWRITE(0);
    __syncthreads();
    CLOAD(32);                 // chunk1 in flight under COMPUTE(0)
    CCOMP(0, 0);
    CWRITE(1);
    __syncthreads();
    CLOAD(64);                 // chunk2 in flight under COMPUTE(1)
    CCOMP(1, 1);
    CWRITE(0);                 // safe: all waves left chunk0 at last barrier
    __syncthreads();
    CCOMP(0, 2);

    int ro[3][4];
    #pragma unroll
    for (int i = 0; i < 3; ++i) {
        const int lg = 2 + i;
        const int ws = 1 << lg;
        const int sft = ws >> 1;
        const int nblk = 256 >> lg;
        int h  = (hh - sft) & 255;
        int nbrow = (b*nblk + (h >> lg))*nblk;
        int hr = h & (ws-1);
        #pragma unroll
        for (int cf = 0; cf < 4; ++cf) {
            int w = (ww0 + cf*16 + lo - sft) & 255;
            ro[i][cf] = (nbrow + (w >> lg))*(ws*ws) + hr*ws + (w & (ws-1));
        }
    }
    #pragma unroll
    for (int rf = 0; rf < 3; ++rf) {
        const int base = wv*48 + rf*16;        // multiple of 16
        const int o0i  = base + hi*4;
        const int sc   = base >> 6;
        const bool isv = (base & 32) != 0;
        const int c32  = o0i & 31;
        float4 bi = *reinterpret_cast<const float4*>(bs + o0i);
        _Float16* tb = (sc == 0) ? (isv ? v0 : q0)
                     : (sc == 1) ? (isv ? v1 : q1)
                                 : (isv ? v2 : q2);
        #pragma unroll
        for (int cf = 0; cf < 4; ++cf) {
            f16x4 hv;
            hv[0] = (_Float16)(acc[rf][cf][0] + bi.x);
            hv[1] = (_Float16)(acc[rf][cf][1] + bi.y);
            hv[2] = (_Float16)(acc[rf][cf][2] + bi.z);
            hv[3] = (_Float16)(acc[rf][cf][3] + bi.w);
            *reinterpret_cast<f16x4*>(tb + (size_t)ro[sc][cf]*32 + c32) = hv;
        }
    }
#undef CLOAD
#undef CWRITE
#undef CCOMP
}

// ---- Flash attention body (r13 verbatim: per-rb fused P+PV) ---------------
template<int GROUP>
__device__ __forceinline__ void attn_body(
    int bid, uint4* Kl, _Float16* Vt, _Float16* Pl,
    const _Float16* __restrict__ Q, const _Float16* __restrict__ Ks,
    const _Float16* Vs, _Float16* O)
{
    constexpr int S   = (GROUP==0) ? 16 : (GROUP==1) ? 64 : 256;
    constexpr int GB  = 256 / S;
    constexpr int KT  = (S < 32) ? 16 : 32;
    constexpr int NT  = S / KT;
    constexpr int CBS = KT / 16;

    const int t = threadIdx.x;
    {
        const int g = t / S, j = t % S;
        const int bq = bid * GB + g;
        int krow, vrow;
        if constexpr (GROUP == 0) {
            krow = (bq >> 2)*64  + (j << 2) + (bq & 3);
            vrow = (bq >> 4)*256 + (j << 4) + (bq & 15);
        } else if constexpr (GROUP == 1) {
            krow = (bq >> 2)*256 + (j << 2) + (bq & 3);
            vrow = ((bq << 2) + (j & 3))*16 + (j >> 2);
        } else {
            krow = ((bq << 4) + (j & 15))*16 + (j >> 4);
            vrow = ((bq << 2) + (j & 3))*64 + (j >> 2);
        }
        const uint4* ks = reinterpret_cast<const uint4*>(Ks + (size_t)krow*32);
        uint4 ka = ks[0], kb = ks[1], kc = ks[2], kd = ks[3];
        Kl[0*256 + t] = ka; Kl[1*256 + t] = kb;
        Kl[2*256 + t] = kc; Kl[3*256 + t] = kd;
        union { uint4 u4[4]; _Float16 h[32]; } vb;
        const uint4* vs = reinterpret_cast<const uint4*>(Vs + (size_t)vrow*32);
        vb.u4[0] = vs[0]; vb.u4[1] = vs[1]; vb.u4[2] = vs[2]; vb.u4[3] = vs[3];
        #pragma unroll
        for (int d = 0; d < 32; ++d) Vt[d*264 + t] = vb.h[d];
        Vt[(t >> 3)*264 + 256 + (t & 7)] = (_Float16)0.f;
        if (t < 8) Vt[32*264 + t] = (_Float16)0.f;
    }
    const int wv = t >> 6, ln = t & 63;
    const int lo = ln & 15, hi = ln >> 4;
    _Float16* Pw = Pl + wv*(16*40);
    if constexpr (S == 16) {
        uint* pw32 = reinterpret_cast<uint*>(Pw);
        pw32[(ln >> 2)*20 +  8 + (ln & 3)] = 0u;
        pw32[(ln >> 2)*20 + 12 + (ln & 3)] = 0u;
    }
    __syncthreads();

    const int rowbase = bid*256 + wv*64;
    f16x8 qf[4];
    #pragma unroll
    for (int rb = 0; rb < 4; ++rb) {
        uint4 qv = *reinterpret_cast<const uint4*>(
            Q + ((size_t)(rowbase + rb*16 + lo))*32 + hi*8);
        qf[rb] = __builtin_bit_cast(f16x8, qv);
    }

    f32x4 ofr[4][2];
    float m[4], ls[4];
    #pragma unroll
    for (int rb = 0; rb < 4; ++rb) {
        m[rb] = -1e30f; ls[rb] = 0.f;
        ofr[rb][0] = f32x4{0.f,0.f,0.f,0.f};
        ofr[rb][1] = f32x4{0.f,0.f,0.f,0.f};
    }
    const f32x4 zf = f32x4{0.f,0.f,0.f,0.f};

    for (int tt = 0; tt < NT; ++tt) {
        f16x8 bk[CBS];
        if constexpr (S != 16) {
            const int wb = (S == 64) ? wv*64 : 0;
            #pragma unroll
            for (int cb = 0; cb < CBS; ++cb) {
                int key = wb + tt*KT + cb*16 + lo;
                bk[cb] = __builtin_bit_cast(f16x8, Kl[hi*256 + key]);
            }
        }

        #pragma unroll
        for (int rb = 0; rb < 4; ++rb) {
            f32x4 sf[CBS];
            if constexpr (S == 16) {
                int key = wv*64 + rb*16 + lo;
                f16x8 bk0 = __builtin_bit_cast(f16x8, Kl[hi*256 + key]);
                sf[0] = __builtin_amdgcn_mfma_f32_16x16x32_f16(bk0, qf[rb], zf, 0,0,0);
            } else {
                #pragma unroll
                for (int cb = 0; cb < CBS; ++cb)
                    sf[cb] = __builtin_amdgcn_mfma_f32_16x16x32_f16(bk[cb], qf[rb], zf, 0,0,0);
            }

            float tm = sf[0][0];
            #pragma unroll
            for (int cb = 0; cb < CBS; ++cb)
                #pragma unroll
                for (int r = 0; r < 4; ++r)
                    if (cb | r) tm = fmaxf(tm, sf[cb][r]);
            tm = fmaxf(tm, __shfl_xor(tm, 16));
            tm = fmaxf(tm, __shfl_xor(tm, 32));
            float mn = fmaxf(m[rb], tm);
            float sc = exp2_fast(m[rb] - mn);
            m[rb] = mn;
            float ps = 0.f;
            #pragma unroll
            for (int cb = 0; cb < CBS; ++cb) {
                float p0 = exp2_fast(sf[cb][0] - mn);
                float p1 = exp2_fast(sf[cb][1] - mn);
                float p2 = exp2_fast(sf[cb][2] - mn);
                float p3 = exp2_fast(sf[cb][3] - mn);
                ps += (p0+p1)+(p2+p3);
                unsigned w01 = pkrtz(p0, p1);
                unsigned w23 = pkrtz(p2, p3);
                _Float16* pp = Pw + lo*40 + cb*16 + hi*4;
                *reinterpret_cast<unsigned*>(pp)     = w01;
                *reinterpret_cast<unsigned*>(pp + 2) = w23;
            }
            ls[rb] = ls[rb]*sc + ps;
            float s0 = __shfl(sc, hi*4 + 0);
            float s1 = __shfl(sc, hi*4 + 1);
            float s2 = __shfl(sc, hi*4 + 2);
            float s3 = __shfl(sc, hi*4 + 3);
            ofr[rb][0][0]*=s0; ofr[rb][0][1]*=s1; ofr[rb][0][2]*=s2; ofr[rb][0][3]*=s3;
            ofr[rb][1][0]*=s0; ofr[rb][1][1]*=s1; ofr[rb][1][2]*=s2; ofr[rb][1][3]*=s3;

            f16x8 pa = *reinterpret_cast<const f16x8*>(Pw + lo*40 + hi*8);
            const int wb2 = (S == 16) ? wv*64 + rb*16 : (S == 64) ? wv*64 : 0;
            const int key0 = wb2 + tt*KT + hi*8;
            #pragma unroll
            for (int dcb = 0; dcb < 2; ++dcb) {
                f16x8 bv = *reinterpret_cast<const f16x8*>(Vt + (dcb*16 + lo)*264 + key0);
                ofr[rb][dcb] = __builtin_amdgcn_mfma_f32_16x16x32_f16(pa, bv, ofr[rb][dcb], 0,0,0);
            }
        }
    }

    #pragma unroll
    for (int rb = 0; rb < 4; ++rb) {
        float v = ls[rb];
        v += __shfl_xor(v, 16);
        v += __shfl_xor(v, 32);
        float linv = 1.f / v;
        float l0 = __shfl(linv, hi*4 + 0);
        float l1 = __shfl(linv, hi*4 + 1);
        float l2 = __shfl(linv, hi*4 + 2);
        float l3 = __shfl(linv, hi*4 + 3);
        #pragma unroll
        for (int dcb = 0; dcb < 2; ++dcb) {
            float lr[4] = {l0, l1, l2, l3};
            #pragma unroll
            for (int r = 0; r < 4; ++r) {
                float ov = ofr[rb][dcb][r] * lr[r];
                int row = rowbase + rb*16 + hi*4 + r;
                O[(size_t)row*32 + dcb*16 + lo] = (_Float16)ov;
            }
        }
    }
}

__global__ __launch_bounds__(256) void k_attn_all(
    const _Float16* __restrict__ q0, const _Float16* __restrict__ v0,
    const _Float16* __restrict__ q1, const _Float16* __restrict__ v1,
    const _Float16* __restrict__ q2, const _Float16* __restrict__ v2)
{
    __shared__ __align__(16) char smem[16384 + 16912 + 5120];
    uint4*    Kl = reinterpret_cast<uint4*>(smem);
    _Float16* Vt = reinterpret_cast<_Float16*>(smem + 16384);
    _Float16* Pl = reinterpret_cast<_Float16*>(smem + 16384 + 16912);
    const int bid = (int)blockIdx.x;
    if (bid < 2048)
        attn_body<0>(bid, Kl, Vt, Pl, q0, q1, v2, const_cast<_Float16*>(v2));
    else if (bid < 4096)
        attn_body<1>(bid - 2048, Kl, Vt, Pl, q1, q2, v0, const_cast<_Float16*>(v0));
    else
        attn_body<2>(bid - 4096, Kl, Vt, Pl, q2, q0, v1, const_cast<_Float16*>(v1));
}

// ---- conv_out (r13 verbatim) ----------------------------------------------
__global__ __launch_bounds__(256) void k_conv_out(
    const _Float16* __restrict__ o0, const _Float16* __restrict__ o1,
    const _Float16* __restrict__ o2, const _Float16* __restrict__ wo,
    const float* __restrict__ b_out, float* __restrict__ out)
{
    constexpr int YS = 104;
    __shared__ _Float16 yt[256*YS];
    const int t  = threadIdx.x;
    const int wv = t >> 6, ln = t & 63;
    const int lo = ln & 15, hi = ln >> 4;
    const int bid = (int)blockIdx.x;
    const int swz = (bid & 7)*256 + (bid >> 3);
    const int b = swz >> 8;
    const int h = swz & 255;

    #pragma unroll
    for (int i = 0; i < 3; ++i) {
        const int lg = 2 + i;
        const int ws = 1 << lg;
        const int sft = ws >> 1;
        const int nblk = 256 >> lg;
        int hh = (h - sft) & 255;
        int w  = (t - sft) & 255;
        int nb = (b*nblk + (hh >> lg))*nblk + (w >> lg);
        int roff = nb*(ws*ws) + (hh & (ws-1))*ws + (w & (ws-1));
        const uint4* src = reinterpret_cast<const uint4*>(
            (i==0 ? o0 : i==1 ? o1 : o2) + (size_t)roff*32);
        uint4 r0 = src[0], r1 = src[1], r2 = src[2], r3 = src[3];
        uint4* dst = reinterpret_cast<uint4*>(&yt[t*YS + i*32]);
        dst[0] = r0; dst[1] = r1; dst[2] = r2; dst[3] = r3;
    }

    f16x8 af[6][3];
    #pragma unroll
    for (int rf = 0; rf < 6; ++rf)
        #pragma unroll
        for (int ks = 0; ks < 3; ++ks)
            af[rf][ks] = *reinterpret_cast<const f16x8*>(
                wo + (rf*16 + lo)*96 + ks*32 + hi*8);
    __syncthreads();

    f32x4 acc[6][4];
    #pragma unroll
    for (int rf = 0; rf < 6; ++rf)
        #pragma unroll
        for (int cf = 0; cf < 4; ++cf) acc[rf][cf] = f32x4{0.f,0.f,0.f,0.f};

    #pragma unroll
    for (int cf = 0; cf < 4; ++cf) {
        const int px = wv*64 + cf*16 + lo;
        #pragma unroll
        for (int ks = 0; ks < 3; ++ks) {
            f16x8 bfv = *reinterpret_cast<const f16x8*>(&yt[px*YS + ks*32 + hi*8]);
            #pragma unroll
            for (int rf = 0; rf < 6; ++rf)
                acc[rf][cf] = __builtin_amdgcn_mfma_f32_16x16x32_f16(
                                  af[rf][ks], bfv, acc[rf][cf], 0,0,0);
        }
    }

    const size_t obase = (size_t)b*96*65536 + (size_t)h*256;
    #pragma unroll
    for (int rf = 0; rf < 6; ++rf) {
        const int oo = rf*16 + hi*4;
        float4 bi = *reinterpret_cast<const float4*>(b_out + oo);
        #pragma unroll
        for (int cf = 0; cf < 4; ++cf) {
            const int px = wv*64 + cf*16 + lo;
            out[obase + (size_t)(oo+0)*65536 + px] = acc[rf][cf][0] + bi.x;
            out[obase + (size_t)(oo+1)*65536 + px] = acc[rf][cf][1] + bi.y;
            out[obase + (size_t)(oo+2)*65536 + px] = acc[rf][cf][2] + bi.z;
            out[obase + (size_t)(oo+3)*65536 + px] = acc[rf][cf][3] + bi.w;
        }
    }
}

extern "C" void kernel_launch(void* const* d_in, const int* in_sizes, int n_in,
                              void* d_out, int out_size, void* d_ws, size_t ws_size,
                              hipStream_t stream)
{
    const float* x     = (const float*)d_in[0];
    const float* w_in  = (const float*)d_in[1];
    const float* b_in  = (const float*)d_in[2];
    const float* gma   = (const float*)d_in[3];
    const float* bta   = (const float*)d_in[4];
    const float* mu    = (const float*)d_in[5];
    const float* var   = (const float*)d_in[6];
    const float* w_out = (const float*)d_in[7];
    const float* b_out = (const float*)d_in[8];
    float* out = (float*)d_out;

    _Float16* W = (_Float16*)d_ws;
    const size_t M = 16777216;
    _Float16 *q0 = W,       *v0 = W +   M, *q1 = W + 2*M,
             *v1 = W + 3*M, *q2 = W + 4*M, *v2 = W + 5*M;
    _Float16* wf = W + 6*M;
    float*    bs = (float*)(W + 6*M + 18432);
    _Float16* wo = W + 6*M + 18432 + 384;

    k_prep<<<1, 256, 0, stream>>>(w_in, b_in, gma, bta, mu, var, w_out, wf, bs, wo);
    k_conv_in<<<8192, 256, 0, stream>>>(x, wf, bs, q0, v0, q1, v1, q2, v2);
    k_attn_all<<<6144, 256, 0, stream>>>(q0, v0, q1, v1, q2, v2);
    k_conv_out<<<2048, 256, 0, stream>>>(v2, v0, v1, wo, b_out, out);
}

// Round 16
// 255.309 us; speedup vs baseline: 1.0825x; 1.0709x over previous
//
#include <hip/hip_runtime.h>

// GMSA r16: conv_in epilogue coalesced via LDS transpose: acc -> LDS
// [64px][200 f16] -> px-major 16B stores (6/thread, full-cacheline runs).
// Kills the 8B-scatter store-transaction wall (r15 showed occupancy is not
// the limiter). attn/conv_out r13 verbatim.

typedef _Float16 f16x8 __attribute__((ext_vector_type(8)));
typedef _Float16 f16x4 __attribute__((ext_vector_type(4)));
typedef float    f32x4 __attribute__((ext_vector_type(4)));

__device__ inline float exp2_fast(float x) {
    float r; asm("v_exp_f32 %0, %1" : "=v"(r) : "v"(x)); return r;
}
__device__ inline unsigned pkrtz(float a, float b) {
    return __builtin_bit_cast(unsigned, __builtin_amdgcn_cvt_pkrtz(a, b));
}

// ---- one-shot weight prep -------------------------------------------------
__global__ __launch_bounds__(256) void k_prep(
    const float* __restrict__ w_in, const float* __restrict__ b_in,
    const float* __restrict__ gma, const float* __restrict__ bta,
    const float* __restrict__ mu,  const float* __restrict__ var,
    const float* __restrict__ w_out,
    _Float16* __restrict__ wf, float* __restrict__ bs, _Float16* __restrict__ wo)
{
    const int t = threadIdx.x;
    if (t < 192) {
        const float qs = ((t & 63) < 32) ? 1.2011224087864498f : 1.0f; // sqrt(log2e)
        float iv = gma[t] * rsqrtf(var[t] + 1e-5f);
        float s  = iv * qs;
        bs[t] = (b_in[t]*iv + bta[t] - mu[t]*iv) * qs;
        #pragma unroll
        for (int c4 = 0; c4 < 96; c4 += 4) {
            float4 w = *reinterpret_cast<const float4*>(w_in + t*96 + c4);
            f16x4 h;
            h[0]=(_Float16)(w.x*s); h[1]=(_Float16)(w.y*s);
            h[2]=(_Float16)(w.z*s); h[3]=(_Float16)(w.w*s);
            *reinterpret_cast<f16x4*>(wf + t*96 + c4) = h;
        }
    }
    if (t < 96) {
        #pragma unroll
        for (int c4 = 0; c4 < 96; c4 += 4) {
            float4 w = *reinterpret_cast<const float4*>(w_out + t*96 + c4);
            f16x4 h;
            h[0]=(_Float16)w.x; h[1]=(_Float16)w.y;
            h[2]=(_Float16)w.z; h[3]=(_Float16)w.w;
            *reinterpret_cast<f16x4*>(wo + t*96 + c4) = h;
        }
    }
}

// ---- conv_in: 64-px tile, 4 waves x (48 o x 64 px), coalesced epilogue ----
__global__ __launch_bounds__(256) void k_conv_in(
    const float* __restrict__ x, const _Float16* __restrict__ wf,
    const float* __restrict__ bs,
    _Float16* __restrict__ q0, _Float16* __restrict__ v0,
    _Float16* __restrict__ q1, _Float16* __restrict__ v1,
    _Float16* __restrict__ q2, _Float16* __restrict__ v2)
{
    __shared__ __align__(16) char smem[64*200*2];   // arena: xs2 then yt
    unsigned (*xs2)[16*68] = reinterpret_cast<unsigned(*)[16*68]>(smem);
    _Float16* yt = reinterpret_cast<_Float16*>(smem);  // [64 px][200 f16]

    const int t  = threadIdx.x;
    const int wv = t >> 6, ln = t & 63;
    const int lo = ln & 15, hi = ln >> 4;

    const int bid  = (int)blockIdx.x;
    const int tile = (bid & 7)*1024 + (bid >> 3);   // XCD-contiguous px ranges
    const int pixbase = tile * 64;
    const int b   = pixbase >> 16;
    const int rem = pixbase & 65535;
    const int hh  = rem >> 8;
    const int ww0 = rem & 255;

    const int r0 = t >> 4;                // pair-row 0..15
    const int q4 = (t & 15) << 2;
    const float* xb = x + (size_t)b*96*65536 + rem + q4;

    float4 L0, L1;

#define CLOAD(c0) { \
    L0 = *reinterpret_cast<const float4*>(xb + (size_t)(c0 + 2*r0    )*65536); \
    L1 = *reinterpret_cast<const float4*>(xb + (size_t)(c0 + 2*r0 + 1)*65536); }
#define CWRITE(bf) { \
    uint4 u0; \
    u0.x = pkrtz(L0.x, L1.x); u0.y = pkrtz(L0.y, L1.y); \
    u0.z = pkrtz(L0.z, L1.z); u0.w = pkrtz(L0.w, L1.w); \
    *reinterpret_cast<uint4*>(&xs2[bf][r0*68 + q4]) = u0; }
#define CCOMP(bf, ks) { \
    _Pragma("unroll") for (int cf = 0; cf < 4; ++cf) { \
        const unsigned* bp = &xs2[bf][hi*4*68 + cf*16 + lo]; \
        uint4 u; u.x = bp[0]; u.y = bp[68]; u.z = bp[136]; u.w = bp[204]; \
        f16x8 bfv = __builtin_bit_cast(f16x8, u); \
        _Pragma("unroll") for (int rf = 0; rf < 3; ++rf) \
            acc[rf][cf] = __builtin_amdgcn_mfma_f32_16x16x32_f16( \
                              af[rf][ks], bfv, acc[rf][cf], 0,0,0); } }

    CLOAD(0);

    f16x8 af[3][3];
    const _Float16* wrow0 = wf + (size_t)(wv*48 + lo)*96 + hi*8;
    #pragma unroll
    for (int rf = 0; rf < 3; ++rf)
        #pragma unroll
        for (int ks = 0; ks < 3; ++ks)
            af[rf][ks] = *reinterpret_cast<const f16x8*>(wrow0 + rf*16*96 + ks*32);

    f32x4 acc[3][4];
    #pragma unroll
    for (int rf = 0; rf < 3; ++rf)
        #pragma unroll
        for (int cf = 0; cf < 4; ++cf) acc[rf][cf] = f32x4{0.f,0.f,0.f,0.f};

    CWRITE(0);
    __syncthreads();
    CLOAD(32);                 // chunk1 in flight under COMPUTE(0)
    CCOMP(0, 0);
    CWRITE(1);
    __syncthreads();
    CLOAD(64);                 // chunk2 in flight under COMPUTE(1)
    CCOMP(1, 1);
    CWRITE(0);                 // safe: all waves left chunk0 at last barrier
    __syncthreads();
    CCOMP(0, 2);

    // epilogue: acc+bias -> yt [px][200], then px-major coalesced stores
    __syncthreads();           // all xs2 reads done before arena reuse
    #pragma unroll
    for (int rf = 0; rf < 3; ++rf) {
        const int o0i = wv*48 + rf*16 + hi*4;   // channel index 0..191
        float4 bi = *reinterpret_cast<const float4*>(bs + o0i);
        #pragma unroll
        for (int cf = 0; cf < 4; ++cf) {
            f16x4 hv;
            hv[0] = (_Float16)(acc[rf][cf][0] + bi.x);
            hv[1] = (_Float16)(acc[rf][cf][1] + bi.y);
            hv[2] = (_Float16)(acc[rf][cf][2] + bi.z);
            hv[3] = (_Float16)(acc[rf][cf][3] + bi.w);
            *reinterpret_cast<f16x4*>(&yt[(cf*16 + lo)*200 + o0i]) = hv;
        }
    }
    __syncthreads();
    {
        const int px = t >> 2, ck = t & 3;     // px-major: lanes fill cachelines
        int rof[3];
        #pragma unroll
        for (int i = 0; i < 3; ++i) {
            const int lg = 2 + i;
            const int ws = 1 << lg;
            const int sft = ws >> 1;
            const int nblk = 256 >> lg;
            int h = (hh - sft) & 255;
            int w = (ww0 + px - sft) & 255;
            rof[i] = ((b*nblk + (h >> lg))*nblk + (w >> lg))*(ws*ws)
                   + (h & (ws-1))*ws + (w & (ws-1));
        }
        const _Float16* yp = yt + px*200 + ck*8;
        uint4 v;
        v = *reinterpret_cast<const uint4*>(yp +   0);
        *reinterpret_cast<uint4*>(q0 + (size_t)rof[0]*32 + ck*8) = v;
        v = *reinterpret_cast<const uint4*>(yp +  32);
        *reinterpret_cast<uint4*>(v0 + (size_t)rof[0]*32 + ck*8) = v;
        v = *reinterpret_cast<const uint4*>(yp +  64);
        *reinterpret_cast<uint4*>(q1 + (size_t)rof[1]*32 + ck*8) = v;
        v = *reinterpret_cast<const uint4*>(yp +  96);
        *reinterpret_cast<uint4*>(v1 + (size_t)rof[1]*32 + ck*8) = v;
        v = *reinterpret_cast<const uint4*>(yp + 128);
        *reinterpret_cast<uint4*>(q2 + (size_t)rof[2]*32 + ck*8) = v;
        v = *reinterpret_cast<const uint4*>(yp + 160);
        *reinterpret_cast<uint4*>(v2 + (size_t)rof[2]*32 + ck*8) = v;
    }
#undef CLOAD
#undef CWRITE
#undef CCOMP
}

// ---- Flash attention body (r13 verbatim: per-rb fused P+PV) ---------------
template<int GROUP>
__device__ __forceinline__ void attn_body(
    int bid, uint4* Kl, _Float16* Vt, _Float16* Pl,
    const _Float16* __restrict__ Q, const _Float16* __restrict__ Ks,
    const _Float16* Vs, _Float16* O)
{
    constexpr int S   = (GROUP==0) ? 16 : (GROUP==1) ? 64 : 256;
    constexpr int GB  = 256 / S;
    constexpr int KT  = (S < 32) ? 16 : 32;
    constexpr int NT  = S / KT;
    constexpr int CBS = KT / 16;

    const int t = threadIdx.x;
    {
        const int g = t / S, j = t % S;
        const int bq = bid * GB + g;
        int krow, vrow;
        if constexpr (GROUP == 0) {
            krow = (bq >> 2)*64  + (j << 2) + (bq & 3);
            vrow = (bq >> 4)*256 + (j << 4) + (bq & 15);
        } else if constexpr (GROUP == 1) {
            krow = (bq >> 2)*256 + (j << 2) + (bq & 3);
            vrow = ((bq << 2) + (j & 3))*16 + (j >> 2);
        } else {
            krow = ((bq << 4) + (j & 15))*16 + (j >> 4);
            vrow = ((bq << 2) + (j & 3))*64 + (j >> 2);
        }
        const uint4* ks = reinterpret_cast<const uint4*>(Ks + (size_t)krow*32);
        uint4 ka = ks[0], kb = ks[1], kc = ks[2], kd = ks[3];
        Kl[0*256 + t] = ka; Kl[1*256 + t] = kb;
        Kl[2*256 + t] = kc; Kl[3*256 + t] = kd;
        union { uint4 u4[4]; _Float16 h[32]; } vb;
        const uint4* vs = reinterpret_cast<const uint4*>(Vs + (size_t)vrow*32);
        vb.u4[0] = vs[0]; vb.u4[1] = vs[1]; vb.u4[2] = vs[2]; vb.u4[3] = vs[3];
        #pragma unroll
        for (int d = 0; d < 32; ++d) Vt[d*264 + t] = vb.h[d];
        Vt[(t >> 3)*264 + 256 + (t & 7)] = (_Float16)0.f;
        if (t < 8) Vt[32*264 + t] = (_Float16)0.f;
    }
    const int wv = t >> 6, ln = t & 63;
    const int lo = ln & 15, hi = ln >> 4;
    _Float16* Pw = Pl + wv*(16*40);
    if constexpr (S == 16) {
        uint* pw32 = reinterpret_cast<uint*>(Pw);
        pw32[(ln >> 2)*20 +  8 + (ln & 3)] = 0u;
        pw32[(ln >> 2)*20 + 12 + (ln & 3)] = 0u;
    }
    __syncthreads();

    const int rowbase = bid*256 + wv*64;
    f16x8 qf[4];
    #pragma unroll
    for (int rb = 0; rb < 4; ++rb) {
        uint4 qv = *reinterpret_cast<const uint4*>(
            Q + ((size_t)(rowbase + rb*16 + lo))*32 + hi*8);
        qf[rb] = __builtin_bit_cast(f16x8, qv);
    }

    f32x4 ofr[4][2];
    float m[4], ls[4];
    #pragma unroll
    for (int rb = 0; rb < 4; ++rb) {
        m[rb] = -1e30f; ls[rb] = 0.f;
        ofr[rb][0] = f32x4{0.f,0.f,0.f,0.f};
        ofr[rb][1] = f32x4{0.f,0.f,0.f,0.f};
    }
    const f32x4 zf = f32x4{0.f,0.f,0.f,0.f};

    for (int tt = 0; tt < NT; ++tt) {
        f16x8 bk[CBS];
        if constexpr (S != 16) {
            const int wb = (S == 64) ? wv*64 : 0;
            #pragma unroll
            for (int cb = 0; cb < CBS; ++cb) {
                int key = wb + tt*KT + cb*16 + lo;
                bk[cb] = __builtin_bit_cast(f16x8, Kl[hi*256 + key]);
            }
        }

        #pragma unroll
        for (int rb = 0; rb < 4; ++rb) {
            f32x4 sf[CBS];
            if constexpr (S == 16) {
                int key = wv*64 + rb*16 + lo;
                f16x8 bk0 = __builtin_bit_cast(f16x8, Kl[hi*256 + key]);
                sf[0] = __builtin_amdgcn_mfma_f32_16x16x32_f16(bk0, qf[rb], zf, 0,0,0);
            } else {
                #pragma unroll
                for (int cb = 0; cb < CBS; ++cb)
                    sf[cb] = __builtin_amdgcn_mfma_f32_16x16x32_f16(bk[cb], qf[rb], zf, 0,0,0);
            }

            float tm = sf[0][0];
            #pragma unroll
            for (int cb = 0; cb < CBS; ++cb)
                #pragma unroll
                for (int r = 0; r < 4; ++r)
                    if (cb | r) tm = fmaxf(tm, sf[cb][r]);
            tm = fmaxf(tm, __shfl_xor(tm, 16));
            tm = fmaxf(tm, __shfl_xor(tm, 32));
            float mn = fmaxf(m[rb], tm);
            float sc = exp2_fast(m[rb] - mn);
            m[rb] = mn;
            float ps = 0.f;
            #pragma unroll
            for (int cb = 0; cb < CBS; ++cb) {
                float p0 = exp2_fast(sf[cb][0] - mn);
                float p1 = exp2_fast(sf[cb][1] - mn);
                float p2 = exp2_fast(sf[cb][2] - mn);
                float p3 = exp2_fast(sf[cb][3] - mn);
                ps += (p0+p1)+(p2+p3);
                unsigned w01 = pkrtz(p0, p1);
                unsigned w23 = pkrtz(p2, p3);
                _Float16* pp = Pw + lo*40 + cb*16 + hi*4;
                *reinterpret_cast<unsigned*>(pp)     = w01;
                *reinterpret_cast<unsigned*>(pp + 2) = w23;
            }
            ls[rb] = ls[rb]*sc + ps;
            float s0 = __shfl(sc, hi*4 + 0);
            float s1 = __shfl(sc, hi*4 + 1);
            float s2 = __shfl(sc, hi*4 + 2);
            float s3 = __shfl(sc, hi*4 + 3);
            ofr[rb][0][0]*=s0; ofr[rb][0][1]*=s1; ofr[rb][0][2]*=s2; ofr[rb][0][3]*=s3;
            ofr[rb][1][0]*=s0; ofr[rb][1][1]*=s1; ofr[rb][1][2]*=s2; ofr[rb][1][3]*=s3;

            f16x8 pa = *reinterpret_cast<const f16x8*>(Pw + lo*40 + hi*8);
            const int wb2 = (S == 16) ? wv*64 + rb*16 : (S == 64) ? wv*64 : 0;
            const int key0 = wb2 + tt*KT + hi*8;
            #pragma unroll
            for (int dcb = 0; dcb < 2; ++dcb) {
                f16x8 bv = *reinterpret_cast<const f16x8*>(Vt + (dcb*16 + lo)*264 + key0);
                ofr[rb][dcb] = __builtin_amdgcn_mfma_f32_16x16x32_f16(pa, bv, ofr[rb][dcb], 0,0,0);
            }
        }
    }

    #pragma unroll
    for (int rb = 0; rb < 4; ++rb) {
        float v = ls[rb];
        v += __shfl_xor(v, 16);
        v += __shfl_xor(v, 32);
        float linv = 1.f / v;
        float l0 = __shfl(linv, hi*4 + 0);
        float l1 = __shfl(linv, hi*4 + 1);
        float l2 = __shfl(linv, hi*4 + 2);
        float l3 = __shfl(linv, hi*4 + 3);
        #pragma unroll
        for (int dcb = 0; dcb < 2; ++dcb) {
            float lr[4] = {l0, l1, l2, l3};
            #pragma unroll
            for (int r = 0; r < 4; ++r) {
                float ov = ofr[rb][dcb][r] * lr[r];
                int row = rowbase + rb*16 + hi*4 + r;
                O[(size_t)row*32 + dcb*16 + lo] = (_Float16)ov;
            }
        }
    }
}

__global__ __launch_bounds__(256) void k_attn_all(
    const _Float16* __restrict__ q0, const _Float16* __restrict__ v0,
    const _Float16* __restrict__ q1, const _Float16* __restrict__ v1,
    const _Float16* __restrict__ q2, const _Float16* __restrict__ v2)
{
    __shared__ __align__(16) char smem[16384 + 16912 + 5120];
    uint4*    Kl = reinterpret_cast<uint4*>(smem);
    _Float16* Vt = reinterpret_cast<_Float16*>(smem + 16384);
    _Float16* Pl = reinterpret_cast<_Float16*>(smem + 16384 + 16912);
    const int bid = (int)blockIdx.x;
    if (bid < 2048)
        attn_body<0>(bid, Kl, Vt, Pl, q0, q1, v2, const_cast<_Float16*>(v2));
    else if (bid < 4096)
        attn_body<1>(bid - 2048, Kl, Vt, Pl, q1, q2, v0, const_cast<_Float16*>(v0));
    else
        attn_body<2>(bid - 4096, Kl, Vt, Pl, q2, q0, v1, const_cast<_Float16*>(v1));
}

// ---- conv_out (r13 verbatim) ----------------------------------------------
__global__ __launch_bounds__(256) void k_conv_out(
    const _Float16* __restrict__ o0, const _Float16* __restrict__ o1,
    const _Float16* __restrict__ o2, const _Float16* __restrict__ wo,
    const float* __restrict__ b_out, float* __restrict__ out)
{
    constexpr int YS = 104;
    __shared__ _Float16 yt[256*YS];
    const int t  = threadIdx.x;
    const int wv = t >> 6, ln = t & 63;
    const int lo = ln & 15, hi = ln >> 4;
    const int bid = (int)blockIdx.x;
    const int swz = (bid & 7)*256 + (bid >> 3);
    const int b = swz >> 8;
    const int h = swz & 255;

    #pragma unroll
    for (int i = 0; i < 3; ++i) {
        const int lg = 2 + i;
        const int ws = 1 << lg;
        const int sft = ws >> 1;
        const int nblk = 256 >> lg;
        int hh = (h - sft) & 255;
        int w  = (t - sft) & 255;
        int nb = (b*nblk + (hh >> lg))*nblk + (w >> lg);
        int roff = nb*(ws*ws) + (hh & (ws-1))*ws + (w & (ws-1));
        const uint4* src = reinterpret_cast<const uint4*>(
            (i==0 ? o0 : i==1 ? o1 : o2) + (size_t)roff*32);
        uint4 r0 = src[0], r1 = src[1], r2 = src[2], r3 = src[3];
        uint4* dst = reinterpret_cast<uint4*>(&yt[t*YS + i*32]);
        dst[0] = r0; dst[1] = r1; dst[2] = r2; dst[3] = r3;
    }

    f16x8 af[6][3];
    #pragma unroll
    for (int rf = 0; rf < 6; ++rf)
        #pragma unroll
        for (int ks = 0; ks < 3; ++ks)
            af[rf][ks] = *reinterpret_cast<const f16x8*>(
                wo + (rf*16 + lo)*96 + ks*32 + hi*8);
    __syncthreads();

    f32x4 acc[6][4];
    #pragma unroll
    for (int rf = 0; rf < 6; ++rf)
        #pragma unroll
        for (int cf = 0; cf < 4; ++cf) acc[rf][cf] = f32x4{0.f,0.f,0.f,0.f};

    #pragma unroll
    for (int cf = 0; cf < 4; ++cf) {
        const int px = wv*64 + cf*16 + lo;
        #pragma unroll
        for (int ks = 0; ks < 3; ++ks) {
            f16x8 bfv = *reinterpret_cast<const f16x8*>(&yt[px*YS + ks*32 + hi*8]);
            #pragma unroll
            for (int rf = 0; rf < 6; ++rf)
                acc[rf][cf] = __builtin_amdgcn_mfma_f32_16x16x32_f16(
                                  af[rf][ks], bfv, acc[rf][cf], 0,0,0);
        }
    }

    const size_t obase = (size_t)b*96*65536 + (size_t)h*256;
    #pragma unroll
    for (int rf = 0; rf < 6; ++rf) {
        const int oo = rf*16 + hi*4;
        float4 bi = *reinterpret_cast<const float4*>(b_out + oo);
        #pragma unroll
        for (int cf = 0; cf < 4; ++cf) {
            const int px = wv*64 + cf*16 + lo;
            out[obase + (size_t)(oo+0)*65536 + px] = acc[rf][cf][0] + bi.x;
            out[obase + (size_t)(oo+1)*65536 + px] = acc[rf][cf][1] + bi.y;
            out[obase + (size_t)(oo+2)*65536 + px] = acc[rf][cf][2] + bi.z;
            out[obase + (size_t)(oo+3)*65536 + px] = acc[rf][cf][3] + bi.w;
        }
    }
}

extern "C" void kernel_launch(void* const* d_in, const int* in_sizes, int n_in,
                              void* d_out, int out_size, void* d_ws, size_t ws_size,
                              hipStream_t stream)
{
    const float* x     = (const float*)d_in[0];
    const float* w_in  = (const float*)d_in[1];
    const float* b_in  = (const float*)d_in[2];
    const float* gma   = (const float*)d_in[3];
    const float* bta   = (const float*)d_in[4];
    const float* mu    = (const float*)d_in[5];
    const float* var   = (const float*)d_in[6];
    const float* w_out = (const float*)d_in[7];
    const float* b_out = (const float*)d_in[8];
    float* out = (float*)d_out;

    _Float16* W = (_Float16*)d_ws;
    const size_t M = 16777216;
    _Float16 *q0 = W,       *v0 = W +   M, *q1 = W + 2*M,
             *v1 = W + 3*M, *q2 = W + 4*M, *v2 = W + 5*M;
    _Float16* wf = W + 6*M;
    float*    bs = (float*)(W + 6*M + 18432);
    _Float16* wo = W + 6*M + 18432 + 384;

    k_prep<<<1, 256, 0, stream>>>(w_in, b_in, gma, bta, mu, var, w_out, wf, bs, wo);
    k_conv_in<<<8192, 256, 0, stream>>>(x, wf, bs, q0, v0, q1, v1, q2, v2);
    k_attn_all<<<6144, 256, 0, stream>>>(q0, v0, q1, v1, q2, v2);
    k_conv_out<<<2048, 256, 0, stream>>>(v2, v0, v1, wo, b_out, out);
}

// Round 17
// 250.917 us; speedup vs baseline: 1.1014x; 1.0175x over previous
//
#include <hip/hip_runtime.h>

// GMSA r17: attn + defer-max (skip rescale when __all(tm<=m+8), exp2-domain)
// + S=256 group scheduled first (long-pole-first). conv_in r16 (LDS-transpose
// coalesced epilogue), conv_out r13 verbatim.

typedef _Float16 f16x8 __attribute__((ext_vector_type(8)));
typedef _Float16 f16x4 __attribute__((ext_vector_type(4)));
typedef float    f32x4 __attribute__((ext_vector_type(4)));

__device__ inline float exp2_fast(float x) {
    float r; asm("v_exp_f32 %0, %1" : "=v"(r) : "v"(x)); return r;
}
__device__ inline unsigned pkrtz(float a, float b) {
    return __builtin_bit_cast(unsigned, __builtin_amdgcn_cvt_pkrtz(a, b));
}

// ---- one-shot weight prep -------------------------------------------------
__global__ __launch_bounds__(256) void k_prep(
    const float* __restrict__ w_in, const float* __restrict__ b_in,
    const float* __restrict__ gma, const float* __restrict__ bta,
    const float* __restrict__ mu,  const float* __restrict__ var,
    const float* __restrict__ w_out,
    _Float16* __restrict__ wf, float* __restrict__ bs, _Float16* __restrict__ wo)
{
    const int t = threadIdx.x;
    if (t < 192) {
        const float qs = ((t & 63) < 32) ? 1.2011224087864498f : 1.0f; // sqrt(log2e)
        float iv = gma[t] * rsqrtf(var[t] + 1e-5f);
        float s  = iv * qs;
        bs[t] = (b_in[t]*iv + bta[t] - mu[t]*iv) * qs;
        #pragma unroll
        for (int c4 = 0; c4 < 96; c4 += 4) {
            float4 w = *reinterpret_cast<const float4*>(w_in + t*96 + c4);
            f16x4 h;
            h[0]=(_Float16)(w.x*s); h[1]=(_Float16)(w.y*s);
            h[2]=(_Float16)(w.z*s); h[3]=(_Float16)(w.w*s);
            *reinterpret_cast<f16x4*>(wf + t*96 + c4) = h;
        }
    }
    if (t < 96) {
        #pragma unroll
        for (int c4 = 0; c4 < 96; c4 += 4) {
            float4 w = *reinterpret_cast<const float4*>(w_out + t*96 + c4);
            f16x4 h;
            h[0]=(_Float16)w.x; h[1]=(_Float16)w.y;
            h[2]=(_Float16)w.z; h[3]=(_Float16)w.w;
            *reinterpret_cast<f16x4*>(wo + t*96 + c4) = h;
        }
    }
}

// ---- conv_in (r16): 64-px tile, coalesced LDS-transpose epilogue ----------
__global__ __launch_bounds__(256) void k_conv_in(
    const float* __restrict__ x, const _Float16* __restrict__ wf,
    const float* __restrict__ bs,
    _Float16* __restrict__ q0, _Float16* __restrict__ v0,
    _Float16* __restrict__ q1, _Float16* __restrict__ v1,
    _Float16* __restrict__ q2, _Float16* __restrict__ v2)
{
    __shared__ __align__(16) char smem[64*200*2];   // arena: xs2 then yt
    unsigned (*xs2)[16*68] = reinterpret_cast<unsigned(*)[16*68]>(smem);
    _Float16* yt = reinterpret_cast<_Float16*>(smem);  // [64 px][200 f16]

    const int t  = threadIdx.x;
    const int wv = t >> 6, ln = t & 63;
    const int lo = ln & 15, hi = ln >> 4;

    const int bid  = (int)blockIdx.x;
    const int tile = (bid & 7)*1024 + (bid >> 3);   // XCD-contiguous px ranges
    const int pixbase = tile * 64;
    const int b   = pixbase >> 16;
    const int rem = pixbase & 65535;
    const int hh  = rem >> 8;
    const int ww0 = rem & 255;

    const int r0 = t >> 4;                // pair-row 0..15
    const int q4 = (t & 15) << 2;
    const float* xb = x + (size_t)b*96*65536 + rem + q4;

    float4 L0, L1;

#define CLOAD(c0) { \
    L0 = *reinterpret_cast<const float4*>(xb + (size_t)(c0 + 2*r0    )*65536); \
    L1 = *reinterpret_cast<const float4*>(xb + (size_t)(c0 + 2*r0 + 1)*65536); }
#define CWRITE(bf) { \
    uint4 u0; \
    u0.x = pkrtz(L0.x, L1.x); u0.y = pkrtz(L0.y, L1.y); \
    u0.z = pkrtz(L0.z, L1.z); u0.w = pkrtz(L0.w, L1.w); \
    *reinterpret_cast<uint4*>(&xs2[bf][r0*68 + q4]) = u0; }
#define CCOMP(bf, ks) { \
    _Pragma("unroll") for (int cf = 0; cf < 4; ++cf) { \
        const unsigned* bp = &xs2[bf][hi*4*68 + cf*16 + lo]; \
        uint4 u; u.x = bp[0]; u.y = bp[68]; u.z = bp[136]; u.w = bp[204]; \
        f16x8 bfv = __builtin_bit_cast(f16x8, u); \
        _Pragma("unroll") for (int rf = 0; rf < 3; ++rf) \
            acc[rf][cf] = __builtin_amdgcn_mfma_f32_16x16x32_f16( \
                              af[rf][ks], bfv, acc[rf][cf], 0,0,0); } }

    CLOAD(0);

    f16x8 af[3][3];
    const _Float16* wrow0 = wf + (size_t)(wv*48 + lo)*96 + hi*8;
    #pragma unroll
    for (int rf = 0; rf < 3; ++rf)
        #pragma unroll
        for (int ks = 0; ks < 3; ++ks)
            af[rf][ks] = *reinterpret_cast<const f16x8*>(wrow0 + rf*16*96 + ks*32);

    f32x4 acc[3][4];
    #pragma unroll
    for (int rf = 0; rf < 3; ++rf)
        #pragma unroll
        for (int cf = 0; cf < 4; ++cf) acc[rf][cf] = f32x4{0.f,0.f,0.f,0.f};

    CWRITE(0);
    __syncthreads();
    CLOAD(32);
    CCOMP(0, 0);
    CWRITE(1);
    __syncthreads();
    CLOAD(64);
    CCOMP(1, 1);
    CWRITE(0);
    __syncthreads();
    CCOMP(0, 2);

    __syncthreads();           // all xs2 reads done before arena reuse
    #pragma unroll
    for (int rf = 0; rf < 3; ++rf) {
        const int o0i = wv*48 + rf*16 + hi*4;
        float4 bi = *reinterpret_cast<const float4*>(bs + o0i);
        #pragma unroll
        for (int cf = 0; cf < 4; ++cf) {
            f16x4 hv;
            hv[0] = (_Float16)(acc[rf][cf][0] + bi.x);
            hv[1] = (_Float16)(acc[rf][cf][1] + bi.y);
            hv[2] = (_Float16)(acc[rf][cf][2] + bi.z);
            hv[3] = (_Float16)(acc[rf][cf][3] + bi.w);
            *reinterpret_cast<f16x4*>(&yt[(cf*16 + lo)*200 + o0i]) = hv;
        }
    }
    __syncthreads();
    {
        const int px = t >> 2, ck = t & 3;
        int rof[3];
        #pragma unroll
        for (int i = 0; i < 3; ++i) {
            const int lg = 2 + i;
            const int ws = 1 << lg;
            const int sft = ws >> 1;
            const int nblk = 256 >> lg;
            int h = (hh - sft) & 255;
            int w = (ww0 + px - sft) & 255;
            rof[i] = ((b*nblk + (h >> lg))*nblk + (w >> lg))*(ws*ws)
                   + (h & (ws-1))*ws + (w & (ws-1));
        }
        const _Float16* yp = yt + px*200 + ck*8;
        uint4 v;
        v = *reinterpret_cast<const uint4*>(yp +   0);
        *reinterpret_cast<uint4*>(q0 + (size_t)rof[0]*32 + ck*8) = v;
        v = *reinterpret_cast<const uint4*>(yp +  32);
        *reinterpret_cast<uint4*>(v0 + (size_t)rof[0]*32 + ck*8) = v;
        v = *reinterpret_cast<const uint4*>(yp +  64);
        *reinterpret_cast<uint4*>(q1 + (size_t)rof[1]*32 + ck*8) = v;
        v = *reinterpret_cast<const uint4*>(yp +  96);
        *reinterpret_cast<uint4*>(v1 + (size_t)rof[1]*32 + ck*8) = v;
        v = *reinterpret_cast<const uint4*>(yp + 128);
        *reinterpret_cast<uint4*>(q2 + (size_t)rof[2]*32 + ck*8) = v;
        v = *reinterpret_cast<const uint4*>(yp + 160);
        *reinterpret_cast<uint4*>(v2 + (size_t)rof[2]*32 + ck*8) = v;
    }
#undef CLOAD
#undef CWRITE
#undef CCOMP
}

// ---- Flash attention body: per-rb fused P+PV + defer-max (THR=8, exp2) ----
template<int GROUP>
__device__ __forceinline__ void attn_body(
    int bid, uint4* Kl, _Float16* Vt, _Float16* Pl,
    const _Float16* __restrict__ Q, const _Float16* __restrict__ Ks,
    const _Float16* Vs, _Float16* O)
{
    constexpr int S   = (GROUP==0) ? 16 : (GROUP==1) ? 64 : 256;
    constexpr int GB  = 256 / S;
    constexpr int KT  = (S < 32) ? 16 : 32;
    constexpr int NT  = S / KT;
    constexpr int CBS = KT / 16;

    const int t = threadIdx.x;
    {
        const int g = t / S, j = t % S;
        const int bq = bid * GB + g;
        int krow, vrow;
        if constexpr (GROUP == 0) {
            krow = (bq >> 2)*64  + (j << 2) + (bq & 3);
            vrow = (bq >> 4)*256 + (j << 4) + (bq & 15);
        } else if constexpr (GROUP == 1) {
            krow = (bq >> 2)*256 + (j << 2) + (bq & 3);
            vrow = ((bq << 2) + (j & 3))*16 + (j >> 2);
        } else {
            krow = ((bq << 4) + (j & 15))*16 + (j >> 4);
            vrow = ((bq << 2) + (j & 3))*64 + (j >> 2);
        }
        const uint4* ks = reinterpret_cast<const uint4*>(Ks + (size_t)krow*32);
        uint4 ka = ks[0], kb = ks[1], kc = ks[2], kd = ks[3];
        Kl[0*256 + t] = ka; Kl[1*256 + t] = kb;
        Kl[2*256 + t] = kc; Kl[3*256 + t] = kd;
        union { uint4 u4[4]; _Float16 h[32]; } vb;
        const uint4* vs = reinterpret_cast<const uint4*>(Vs + (size_t)vrow*32);
        vb.u4[0] = vs[0]; vb.u4[1] = vs[1]; vb.u4[2] = vs[2]; vb.u4[3] = vs[3];
        #pragma unroll
        for (int d = 0; d < 32; ++d) Vt[d*264 + t] = vb.h[d];
        Vt[(t >> 3)*264 + 256 + (t & 7)] = (_Float16)0.f;
        if (t < 8) Vt[32*264 + t] = (_Float16)0.f;
    }
    const int wv = t >> 6, ln = t & 63;
    const int lo = ln & 15, hi = ln >> 4;
    _Float16* Pw = Pl + wv*(16*40);
    if constexpr (S == 16) {
        uint* pw32 = reinterpret_cast<uint*>(Pw);
        pw32[(ln >> 2)*20 +  8 + (ln & 3)] = 0u;
        pw32[(ln >> 2)*20 + 12 + (ln & 3)] = 0u;
    }
    __syncthreads();

    const int rowbase = bid*256 + wv*64;
    f16x8 qf[4];
    #pragma unroll
    for (int rb = 0; rb < 4; ++rb) {
        uint4 qv = *reinterpret_cast<const uint4*>(
            Q + ((size_t)(rowbase + rb*16 + lo))*32 + hi*8);
        qf[rb] = __builtin_bit_cast(f16x8, qv);
    }

    f32x4 ofr[4][2];
    float m[4], ls[4];
    #pragma unroll
    for (int rb = 0; rb < 4; ++rb) {
        m[rb] = -1e30f; ls[rb] = 0.f;
        ofr[rb][0] = f32x4{0.f,0.f,0.f,0.f};
        ofr[rb][1] = f32x4{0.f,0.f,0.f,0.f};
    }
    const f32x4 zf = f32x4{0.f,0.f,0.f,0.f};

    for (int tt = 0; tt < NT; ++tt) {
        f16x8 bk[CBS];
        if constexpr (S != 16) {
            const int wb = (S == 64) ? wv*64 : 0;
            #pragma unroll
            for (int cb = 0; cb < CBS; ++cb) {
                int key = wb + tt*KT + cb*16 + lo;
                bk[cb] = __builtin_bit_cast(f16x8, Kl[hi*256 + key]);
            }
        }

        #pragma unroll
        for (int rb = 0; rb < 4; ++rb) {
            f32x4 sf[CBS];
            if constexpr (S == 16) {
                int key = wv*64 + rb*16 + lo;
                f16x8 bk0 = __builtin_bit_cast(f16x8, Kl[hi*256 + key]);
                sf[0] = __builtin_amdgcn_mfma_f32_16x16x32_f16(bk0, qf[rb], zf, 0,0,0);
            } else {
                #pragma unroll
                for (int cb = 0; cb < CBS; ++cb)
                    sf[cb] = __builtin_amdgcn_mfma_f32_16x16x32_f16(bk[cb], qf[rb], zf, 0,0,0);
            }

            float tm = sf[0][0];
            #pragma unroll
            for (int cb = 0; cb < CBS; ++cb)
                #pragma unroll
                for (int r = 0; r < 4; ++r)
                    if (cb | r) tm = fmaxf(tm, sf[cb][r]);
            tm = fmaxf(tm, __shfl_xor(tm, 16));
            tm = fmaxf(tm, __shfl_xor(tm, 32));

            // defer-max: keep old m when no row grew by >8 (P <= 2^8, f16-safe)
            const bool skip = __all(tm <= m[rb] + 8.f);
            float mn = skip ? m[rb] : fmaxf(m[rb], tm);
            float ps = 0.f;
            #pragma unroll
            for (int cb = 0; cb < CBS; ++cb) {
                float p0 = exp2_fast(sf[cb][0] - mn);
                float p1 = exp2_fast(sf[cb][1] - mn);
                float p2 = exp2_fast(sf[cb][2] - mn);
                float p3 = exp2_fast(sf[cb][3] - mn);
                ps += (p0+p1)+(p2+p3);
                unsigned w01 = pkrtz(p0, p1);
                unsigned w23 = pkrtz(p2, p3);
                _Float16* pp = Pw + lo*40 + cb*16 + hi*4;
                *reinterpret_cast<unsigned*>(pp)     = w01;
                *reinterpret_cast<unsigned*>(pp + 2) = w23;
            }
            if (skip) {
                ls[rb] += ps;
            } else {
                float sc = exp2_fast(m[rb] - mn);
                m[rb] = mn;
                ls[rb] = ls[rb]*sc + ps;
                float s0 = __shfl(sc, hi*4 + 0);
                float s1 = __shfl(sc, hi*4 + 1);
                float s2 = __shfl(sc, hi*4 + 2);
                float s3 = __shfl(sc, hi*4 + 3);
                ofr[rb][0][0]*=s0; ofr[rb][0][1]*=s1; ofr[rb][0][2]*=s2; ofr[rb][0][3]*=s3;
                ofr[rb][1][0]*=s0; ofr[rb][1][1]*=s1; ofr[rb][1][2]*=s2; ofr[rb][1][3]*=s3;
            }

            f16x8 pa = *reinterpret_cast<const f16x8*>(Pw + lo*40 + hi*8);
            const int wb2 = (S == 16) ? wv*64 + rb*16 : (S == 64) ? wv*64 : 0;
            const int key0 = wb2 + tt*KT + hi*8;
            #pragma unroll
            for (int dcb = 0; dcb < 2; ++dcb) {
                f16x8 bv = *reinterpret_cast<const f16x8*>(Vt + (dcb*16 + lo)*264 + key0);
                ofr[rb][dcb] = __builtin_amdgcn_mfma_f32_16x16x32_f16(pa, bv, ofr[rb][dcb], 0,0,0);
            }
        }
    }

    #pragma unroll
    for (int rb = 0; rb < 4; ++rb) {
        float v = ls[rb];
        v += __shfl_xor(v, 16);
        v += __shfl_xor(v, 32);
        float linv = 1.f / v;
        float l0 = __shfl(linv, hi*4 + 0);
        float l1 = __shfl(linv, hi*4 + 1);
        float l2 = __shfl(linv, hi*4 + 2);
        float l3 = __shfl(linv, hi*4 + 3);
        #pragma unroll
        for (int dcb = 0; dcb < 2; ++dcb) {
            float lr[4] = {l0, l1, l2, l3};
            #pragma unroll
            for (int r = 0; r < 4; ++r) {
                float ov = ofr[rb][dcb][r] * lr[r];
                int row = rowbase + rb*16 + hi*4 + r;
                O[(size_t)row*32 + dcb*16 + lo] = (_Float16)ov;
            }
        }
    }
}

// long-pole-first: G2 (S=256) blocks first, then G1, then G0
__global__ __launch_bounds__(256) void k_attn_all(
    const _Float16* __restrict__ q0, const _Float16* __restrict__ v0,
    const _Float16* __restrict__ q1, const _Float16* __restrict__ v1,
    const _Float16* __restrict__ q2, const _Float16* __restrict__ v2)
{
    __shared__ __align__(16) char smem[16384 + 16912 + 5120];
    uint4*    Kl = reinterpret_cast<uint4*>(smem);
    _Float16* Vt = reinterpret_cast<_Float16*>(smem + 16384);
    _Float16* Pl = reinterpret_cast<_Float16*>(smem + 16384 + 16912);
    const int bid = (int)blockIdx.x;
    if (bid < 2048)
        attn_body<2>(bid, Kl, Vt, Pl, q2, q0, v1, const_cast<_Float16*>(v1));
    else if (bid < 4096)
        attn_body<1>(bid - 2048, Kl, Vt, Pl, q1, q2, v0, const_cast<_Float16*>(v0));
    else
        attn_body<0>(bid - 4096, Kl, Vt, Pl, q0, q1, v2, const_cast<_Float16*>(v2));
}

// ---- conv_out (r13 verbatim) ----------------------------------------------
__global__ __launch_bounds__(256) void k_conv_out(
    const _Float16* __restrict__ o0, const _Float16* __restrict__ o1,
    const _Float16* __restrict__ o2, const _Float16* __restrict__ wo,
    const float* __restrict__ b_out, float* __restrict__ out)
{
    constexpr int YS = 104;
    __shared__ _Float16 yt[256*YS];
    const int t  = threadIdx.x;
    const int wv = t >> 6, ln = t & 63;
    const int lo = ln & 15, hi = ln >> 4;
    const int bid = (int)blockIdx.x;
    const int swz = (bid & 7)*256 + (bid >> 3);
    const int b = swz >> 8;
    const int h = swz & 255;

    #pragma unroll
    for (int i = 0; i < 3; ++i) {
        const int lg = 2 + i;
        const int ws = 1 << lg;
        const int sft = ws >> 1;
        const int nblk = 256 >> lg;
        int hh = (h - sft) & 255;
        int w  = (t - sft) & 255;
        int nb = (b*nblk + (hh >> lg))*nblk + (w >> lg);
        int roff = nb*(ws*ws) + (hh & (ws-1))*ws + (w & (ws-1));
        const uint4* src = reinterpret_cast<const uint4*>(
            (i==0 ? o0 : i==1 ? o1 : o2) + (size_t)roff*32);
        uint4 r0 = src[0], r1 = src[1], r2 = src[2], r3 = src[3];
        uint4* dst = reinterpret_cast<uint4*>(&yt[t*YS + i*32]);
        dst[0] = r0; dst[1] = r1; dst[2] = r2; dst[3] = r3;
    }

    f16x8 af[6][3];
    #pragma unroll
    for (int rf = 0; rf < 6; ++rf)
        #pragma unroll
        for (int ks = 0; ks < 3; ++ks)
            af[rf][ks] = *reinterpret_cast<const f16x8*>(
                wo + (rf*16 + lo)*96 + ks*32 + hi*8);
    __syncthreads();

    f32x4 acc[6][4];
    #pragma unroll
    for (int rf = 0; rf < 6; ++rf)
        #pragma unroll
        for (int cf = 0; cf < 4; ++cf) acc[rf][cf] = f32x4{0.f,0.f,0.f,0.f};

    #pragma unroll
    for (int cf = 0; cf < 4; ++cf) {
        const int px = wv*64 + cf*16 + lo;
        #pragma unroll
        for (int ks = 0; ks < 3; ++ks) {
            f16x8 bfv = *reinterpret_cast<const f16x8*>(&yt[px*YS + ks*32 + hi*8]);
            #pragma unroll
            for (int rf = 0; rf < 6; ++rf)
                acc[rf][cf] = __builtin_amdgcn_mfma_f32_16x16x32_f16(
                                  af[rf][ks], bfv, acc[rf][cf], 0,0,0);
        }
    }

    const size_t obase = (size_t)b*96*65536 + (size_t)h*256;
    #pragma unroll
    for (int rf = 0; rf < 6; ++rf) {
        const int oo = rf*16 + hi*4;
        float4 bi = *reinterpret_cast<const float4*>(b_out + oo);
        #pragma unroll
        for (int cf = 0; cf < 4; ++cf) {
            const int px = wv*64 + cf*16 + lo;
            out[obase + (size_t)(oo+0)*65536 + px] = acc[rf][cf][0] + bi.x;
            out[obase + (size_t)(oo+1)*65536 + px] = acc[rf][cf][1] + bi.y;
            out[obase + (size_t)(oo+2)*65536 + px] = acc[rf][cf][2] + bi.z;
            out[obase + (size_t)(oo+3)*65536 + px] = acc[rf][cf][3] + bi.w;
        }
    }
}

extern "C" void kernel_launch(void* const* d_in, const int* in_sizes, int n_in,
                              void* d_out, int out_size, void* d_ws, size_t ws_size,
                              hipStream_t stream)
{
    const float* x     = (const float*)d_in[0];
    const float* w_in  = (const float*)d_in[1];
    const float* b_in  = (const float*)d_in[2];
    const float* gma   = (const float*)d_in[3];
    const float* bta   = (const float*)d_in[4];
    const float* mu    = (const float*)d_in[5];
    const float* var   = (const float*)d_in[6];
    const float* w_out = (const float*)d_in[7];
    const float* b_out = (const float*)d_in[8];
    float* out = (float*)d_out;

    _Float16* W = (_Float16*)d_ws;
    const size_t M = 16777216;
    _Float16 *q0 = W,       *v0 = W +   M, *q1 = W + 2*M,
             *v1 = W + 3*M, *q2 = W + 4*M, *v2 = W + 5*M;
    _Float16* wf = W + 6*M;
    float*    bs = (float*)(W + 6*M + 18432);
    _Float16* wo = W + 6*M + 18432 + 384;

    k_prep<<<1, 256, 0, stream>>>(w_in, b_in, gma, bta, mu, var, w_out, wf, bs, wo);
    k_conv_in<<<8192, 256, 0, stream>>>(x, wf, bs, q0, v0, q1, v1, q2, v2);
    k_attn_all<<<6144, 256, 0, stream>>>(q0, v0, q1, v1, q2, v2);
    k_conv_out<<<2048, 256, 0, stream>>>(v2, v0, v1, wo, b_out, out);
}